// Round 5
// baseline (2186.978 us; speedup 1.0000x reference)
//
#include <hip/hip_runtime.h>

#define NN 100000     // nodes
#define NE 1600000    // edges before self loops
#define ET 1700000    // NE + NN
#define CH 128        // hidden channels (H*C, H=1)

typedef unsigned int u32;

// flush non-finite to 0 (defense-in-depth; should be a no-op)
__device__ __forceinline__ float sane(float v) {
    return (v == v && v < 1e30f && v > -1e30f) ? v : 0.f;
}

// ---------------------------------------------------------------------------
// chunk1: out_idx[e] = f32(src), out_idx[ET+e] = f32(dst)
// ---------------------------------------------------------------------------
__global__ __launch_bounds__(256) void k_idx(
    const int* __restrict__ ei, float* __restrict__ out_idx)
{
    int e = blockIdx.x * 256 + threadIdx.x;
    if (e >= ET) return;
    int s, d;
    if (e < NE) { s = ei[e]; d = ei[NE + e]; }
    else        { s = d = e - NE; }
    out_idx[e]      = (float)s;
    out_idx[ET + e] = (float)d;
}

// ---------------------------------------------------------------------------
// E1 (wave/edge): logit = att . leaky_relu(xl(src) + xr(dst) + ea@We)
// xl/xr recomputed from x (2.4 MB, cache-resident). exa[e]=exp(logit);
// den[dst] += exa. Softmax max-shift skipped (logits O(1), shift-invariant).
// ---------------------------------------------------------------------------
__global__ __launch_bounds__(256) void k_logits(
    const int* __restrict__ ei, const float* __restrict__ ew,
    const float* __restrict__ x,
    const float* __restrict__ Wl, const float* __restrict__ bl,
    const float* __restrict__ Wr, const float* __restrict__ br,
    const float* __restrict__ We, const float* __restrict__ att,
    float* __restrict__ exa, float* __restrict__ den)
{
    __shared__ float sWl[6][CH], sWr[6][CH], sWe[2][CH];
    __shared__ float sbl[CH], sbr[CH], satt[CH];
    for (int i = threadIdx.x; i < 6 * CH; i += 256) {
        sWl[i / CH][i % CH] = Wl[i];
        sWr[i / CH][i % CH] = Wr[i];
    }
    for (int i = threadIdx.x; i < 2 * CH; i += 256) sWe[i / CH][i % CH] = We[i];
    for (int i = threadIdx.x; i < CH; i += 256) {
        sbl[i] = bl[i]; sbr[i] = br[i]; satt[i] = att[i];
    }
    __syncthreads();

    int lane = threadIdx.x & 63;
    int wv = (blockIdx.x << 2) + (threadIdx.x >> 6);
    int nw = gridDim.x << 2;

    for (int e = wv; e < ET; e += nw) {
        int src, dst; float ea0, ea1;
        if (e < NE) {
            src = ei[e]; dst = ei[NE + e];
            ea0 = ew[2 * e]; ea1 = ew[2 * e + 1];
        } else {
            src = dst = e - NE; ea0 = 0.f; ea1 = 0.f;
        }
        if ((u32)src >= NN) src = 0;
        if ((u32)dst >= NN) dst = 0;
        float xs[6], xd[6];
#pragma unroll
        for (int k = 0; k < 6; ++k) {
            xs[k] = x[src * 6 + k];
            xd[k] = x[dst * 6 + k];
        }
        float p = 0.f;
#pragma unroll
        for (int hh = 0; hh < 2; ++hh) {
            int c = lane + (hh << 6);
            float xlv = sbl[c], xrv = sbr[c];
#pragma unroll
            for (int k = 0; k < 6; ++k) {
                xlv += xs[k] * sWl[k][c];
                xrv += xd[k] * sWr[k][c];
            }
            float m = xlv + xrv + ea0 * sWe[0][c] + ea1 * sWe[1][c];
            m = m > 0.f ? m : 0.2f * m;      // leaky_relu(0.2)
            p += m * satt[c];
        }
#pragma unroll
        for (int off = 32; off; off >>= 1) p += __shfl_down(p, off, 64);
        if (lane == 0) {
            p = fminf(fmaxf(p, -60.f), 60.f);
            float ev = __expf(p);
            exa[e] = ev;
            atomicAdd(den + dst, ev);
        }
    }
}

// ---------------------------------------------------------------------------
// E2: alpha = ex/den; deg[dst] += alpha; f32 alpha to d_out chunk2
// ---------------------------------------------------------------------------
__global__ __launch_bounds__(256) void k_alpha(
    const int* __restrict__ ei, const float* __restrict__ den,
    float* __restrict__ exa, float* __restrict__ deg,
    float* __restrict__ out_alpha)
{
    int e = blockIdx.x * 256 + threadIdx.x;
    if (e >= ET) return;
    int dst = (e < NE) ? ei[NE + e] : e - NE;
    if ((u32)dst >= NN) dst = 0;
    float dn = den[dst];
    float a = (dn > 1e-30f) ? exa[e] / dn : 0.f;
    a = sane(a);
    exa[e] = a;
    out_alpha[e] = a;
    atomicAdd(deg + dst, a);
}

__global__ __launch_bounds__(256) void k_dinv(float* __restrict__ deg)
{
    int n = blockIdx.x * 256 + threadIdx.x;
    if (n >= NN) return;
    float d = deg[n];
    deg[n] = (d > 1e-20f) ? rsqrtf(d) : 0.f;
}

// ---------------------------------------------------------------------------
// E3 (wave/edge): h[dst,:] += alpha * xl(src,:)   (xl recomputed; f32 atomics)
// ---------------------------------------------------------------------------
__global__ __launch_bounds__(256) void k_h(
    const int* __restrict__ ei, const float* __restrict__ alpha,
    const float* __restrict__ x,
    const float* __restrict__ Wl, const float* __restrict__ bl,
    float* __restrict__ h)
{
    __shared__ float sWl[6][CH];
    __shared__ float sbl[CH];
    for (int i = threadIdx.x; i < 6 * CH; i += 256) sWl[i / CH][i % CH] = Wl[i];
    for (int i = threadIdx.x; i < CH; i += 256) sbl[i] = bl[i];
    __syncthreads();

    int lane = threadIdx.x & 63;
    int wv = (blockIdx.x << 2) + (threadIdx.x >> 6);
    int nw = gridDim.x << 2;

    for (int e = wv; e < ET; e += nw) {
        int src, dst;
        if (e < NE) { src = ei[e]; dst = ei[NE + e]; }
        else        { src = dst = e - NE; }
        if ((u32)src >= NN) src = 0;
        if ((u32)dst >= NN) dst = 0;
        float a = alpha[e];
        float xs[6];
#pragma unroll
        for (int k = 0; k < 6; ++k) xs[k] = x[src * 6 + k];
#pragma unroll
        for (int hh = 0; hh < 2; ++hh) {
            int c = lane + (hh << 6);
            float v = sbl[c];
#pragma unroll
            for (int k = 0; k < 6; ++k) v += xs[k] * sWl[k][c];
            atomicAdd(&h[(size_t)dst * CH + c], a * v);
        }
    }
}

// ---------------------------------------------------------------------------
// GEMM1: hg = relu(h + b_gat) @ W2   (W2 from global/L2; srow in LDS)
// ---------------------------------------------------------------------------
__global__ __launch_bounds__(256) void k_gemm1(
    const float* __restrict__ h, const float* __restrict__ bgat,
    const float* __restrict__ W2, float* __restrict__ hg)
{
    __shared__ float srow[2][CH];
    __shared__ float sb[CH];
    if (threadIdx.x < CH) sb[threadIdx.x] = bgat[threadIdx.x];
    __syncthreads();

    int r = threadIdx.x >> 7;
    int c = threadIdx.x & 127;
    for (int np = blockIdx.x; np < NN / 2; np += gridDim.x) {
        int n = 2 * np + r;
        float v = sane(h[(size_t)n * CH + c]) + sb[c];
        srow[r][c] = v > 0.f ? v : 0.f;
        __syncthreads();
        float acc = 0.f;
#pragma unroll 8
        for (int k = 0; k < CH; ++k)
            acc += srow[r][k] * W2[k * CH + c];
        hg[(size_t)n * CH + c] = acc;
        __syncthreads();
    }
}

// ---------------------------------------------------------------------------
// E5 (wave/edge): h2[dst,:] += dinv[src]*alpha*dinv[dst] * hg[src,:]
// ---------------------------------------------------------------------------
__global__ __launch_bounds__(256) void k_h2(
    const int* __restrict__ ei, const float* __restrict__ alpha,
    const float* __restrict__ dinv, const float* __restrict__ hg,
    float* __restrict__ h2)
{
    int e = (blockIdx.x << 2) + (threadIdx.x >> 6);
    if (e >= ET) return;
    int lane = threadIdx.x & 63;
    int src, dst;
    if (e < NE) { src = ei[e]; dst = ei[NE + e]; }
    else        { src = dst = e - NE; }
    if ((u32)src >= NN) src = 0;
    if ((u32)dst >= NN) dst = 0;
    float nrm = dinv[src] * alpha[e] * dinv[dst];
#pragma unroll
    for (int hh = 0; hh < 2; ++hh) {
        int c = lane + (hh << 6);
        atomicAdd(&h2[(size_t)dst * CH + c], nrm * sane(hg[(size_t)src * CH + c]));
    }
}

// ---------------------------------------------------------------------------
// K_out: out[n,:] = relu(h2 + b_gcn) @ W3 + b3    (wave per node)
// ---------------------------------------------------------------------------
__global__ __launch_bounds__(256) void k_final(
    const float* __restrict__ h2, const float* __restrict__ bgcn,
    const float* __restrict__ W3, const float* __restrict__ b3,
    float* __restrict__ out)
{
    __shared__ float sW30[CH], sW31[CH], sbg[CH];
    for (int i = threadIdx.x; i < CH; i += 256) {
        sW30[i] = W3[2 * i];
        sW31[i] = W3[2 * i + 1];
        sbg[i]  = bgcn[i];
    }
    __syncthreads();
    int n = (blockIdx.x << 2) + (threadIdx.x >> 6);
    if (n >= NN) return;
    int lane = threadIdx.x & 63;
    float a0 = 0.f, a1 = 0.f;
#pragma unroll
    for (int hh = 0; hh < 2; ++hh) {
        int c = lane + (hh << 6);
        float v = sane(h2[(size_t)n * CH + c]) + sbg[c];
        v = v > 0.f ? v : 0.f;
        a0 += v * sW30[c];
        a1 += v * sW31[c];
    }
#pragma unroll
    for (int off = 32; off; off >>= 1) {
        a0 += __shfl_down(a0, off, 64);
        a1 += __shfl_down(a1, off, 64);
    }
    if (lane == 0) {
        out[n * 2]     = sane(a0 + b3[0]);
        out[n * 2 + 1] = sane(a1 + b3[1]);
    }
}

// ---------------------------------------------------------------------------
extern "C" void kernel_launch(void* const* d_in, const int* in_sizes, int n_in,
                              void* d_out, int out_size, void* d_ws, size_t ws_size,
                              hipStream_t stream)
{
    const float* x    = (const float*)d_in[0];
    const int*   ei   = (const int*)d_in[1];
    const float* ew   = (const float*)d_in[2];
    const float* Wl   = (const float*)d_in[3];
    const float* bl   = (const float*)d_in[4];
    const float* Wr   = (const float*)d_in[5];
    const float* br   = (const float*)d_in[6];
    const float* We   = (const float*)d_in[7];
    const float* att  = (const float*)d_in[8];
    const float* bgat = (const float*)d_in[9];
    const float* W2   = (const float*)d_in[10];
    const float* bgcn = (const float*)d_in[11];
    const float* W3   = (const float*)d_in[12];
    const float* b3   = (const float*)d_in[13];

    float* out       = (float*)d_out;          // chunk0: out [N,2] f32
    float* out_idx   = out + 200000;           // chunk1: stack([src,dst]) [2,ET]
    float* out_alpha = out + 200000 + 2 * ET;  // chunk2: alpha [ET,1]

    // workspace (f32, 110.4 MB): A[NN*CH] | B[NN*CH] | exa[ET] | den[NN] | deg[NN]
    float* ws  = (float*)d_ws;
    float* A   = ws;                           // h, then h2
    float* B   = A + (size_t)NN * CH;          // hg
    float* exa = B + (size_t)NN * CH;
    float* den = exa + ET;
    float* deg = den + NN;

    hipMemsetAsync(den, 0, NN * sizeof(float), stream);
    hipMemsetAsync(deg, 0, NN * sizeof(float), stream);
    hipMemsetAsync(A, 0, (size_t)NN * CH * sizeof(float), stream);

    k_idx<<<(ET + 255) / 256, 256, 0, stream>>>(ei, out_idx);
    k_logits<<<8192, 256, 0, stream>>>(ei, ew, x, Wl, bl, Wr, br, We, att, exa, den);
    k_alpha<<<(ET + 255) / 256, 256, 0, stream>>>(ei, den, exa, deg, out_alpha);
    k_dinv<<<(NN + 255) / 256, 256, 0, stream>>>(deg);
    k_h<<<8192, 256, 0, stream>>>(ei, exa, x, Wl, bl, A);
    k_gemm1<<<1024, 256, 0, stream>>>(A, bgat, W2, B);
    hipMemsetAsync(A, 0, (size_t)NN * CH * sizeof(float), stream);
    k_h2<<<ET / 4, 256, 0, stream>>>(ei, exa, deg, B, A);
    k_final<<<NN / 4, 256, 0, stream>>>(A, bgcn, W3, b3, out);
}

// Round 6
// 1351.804 us; speedup vs baseline: 1.6178x; 1.6178x over previous
//
#include <hip/hip_runtime.h>

#define NN 100000     // nodes
#define NE 1600000    // edges before self loops
#define ET 1700000    // NE + NN
#define CH 128        // hidden channels (H*C, H=1)

typedef unsigned int u32;

// ---------------------------------------------------------------------------
// chunk1: out_idx[e] = f32(src), out_idx[ET+e] = f32(dst)
// ---------------------------------------------------------------------------
__global__ __launch_bounds__(256) void k_idx(
    const int* __restrict__ ei, float* __restrict__ out_idx)
{
    int e = blockIdx.x * 256 + threadIdx.x;
    if (e >= ET) return;
    int s, d;
    if (e < NE) { s = ei[e]; d = ei[NE + e]; }
    else        { s = d = e - NE; }
    out_idx[e]      = (float)s;
    out_idx[ET + e] = (float)d;
}

// ---------------------------------------------------------------------------
// CSR build: cnt[dst]++  ->  2-level exclusive scan -> scatter edge ids
// ---------------------------------------------------------------------------
__global__ __launch_bounds__(256) void k_deg(
    const int* __restrict__ ei, u32* __restrict__ cnt)
{
    int e = blockIdx.x * 256 + threadIdx.x;
    if (e >= ET) return;
    int d = (e < NE) ? ei[NE + e] : e - NE;
    if ((u32)d >= NN) d = 0;
    atomicAdd(&cnt[d], 1u);
}

__global__ __launch_bounds__(256) void k_scanA(
    const u32* __restrict__ cnt, u32* __restrict__ bsum)
{
    __shared__ u32 s[256];
    int i = blockIdx.x * 256 + threadIdx.x;
    s[threadIdx.x] = (i < NN) ? cnt[i] : 0u;
    __syncthreads();
    for (int off = 128; off; off >>= 1) {
        if (threadIdx.x < off) s[threadIdx.x] += s[threadIdx.x + off];
        __syncthreads();
    }
    if (threadIdx.x == 0) bsum[blockIdx.x] = s[0];
}

__global__ __launch_bounds__(512) void k_scanB(u32* __restrict__ bsum, int nb)
{
    __shared__ u32 s[512];
    int t = threadIdx.x;
    u32 v = (t < nb) ? bsum[t] : 0u;
    s[t] = v; __syncthreads();
    for (int off = 1; off < 512; off <<= 1) {
        u32 a = (t >= off) ? s[t - off] : 0u;
        __syncthreads();
        s[t] += a;
        __syncthreads();
    }
    if (t < nb) bsum[t] = s[t] - v;    // exclusive block offsets
}

__global__ __launch_bounds__(256) void k_scanC(
    const u32* __restrict__ cnt, const u32* __restrict__ bsum,
    u32* __restrict__ rowptr)
{
    __shared__ u32 s[256];
    int i = blockIdx.x * 256 + threadIdx.x;
    u32 v = (i < NN) ? cnt[i] : 0u;
    s[threadIdx.x] = v; __syncthreads();
    for (int off = 1; off < 256; off <<= 1) {
        u32 a = (threadIdx.x >= off) ? s[threadIdx.x - off] : 0u;
        __syncthreads();
        s[threadIdx.x] += a;
        __syncthreads();
    }
    if (i < NN) rowptr[i] = s[threadIdx.x] - v + bsum[blockIdx.x];
    if (i == 0) rowptr[NN] = ET;
}

__global__ __launch_bounds__(256) void k_scatter(
    const int* __restrict__ ei, const u32* __restrict__ rowptr,
    u32* __restrict__ cnt, u32* __restrict__ eid)
{
    int e = blockIdx.x * 256 + threadIdx.x;
    if (e >= ET) return;
    int d = (e < NE) ? ei[NE + e] : e - NE;
    if ((u32)d >= NN) d = 0;
    u32 pos = rowptr[d] + atomicAdd(&cnt[d], 1u);
    eid[pos] = (u32)e;
}

// ---------------------------------------------------------------------------
// E1 (wave/edge): logit = att . leaky_relu(xl(src) + xr(dst) + ea@We)
// writes exp(logit) into out_alpha (d_out chunk2, used as scratch);
// den[dst] += exp. Max-shift skipped (logits O(1), softmax shift-invariant).
// ---------------------------------------------------------------------------
__global__ __launch_bounds__(256) void k_logits(
    const int* __restrict__ ei, const float* __restrict__ ew,
    const float* __restrict__ x,
    const float* __restrict__ Wl, const float* __restrict__ bl,
    const float* __restrict__ Wr, const float* __restrict__ br,
    const float* __restrict__ We, const float* __restrict__ att,
    float* __restrict__ out_alpha, float* __restrict__ den)
{
    __shared__ float sWl[6][CH], sWr[6][CH], sWe[2][CH];
    __shared__ float sbl[CH], sbr[CH], satt[CH];
    for (int i = threadIdx.x; i < 6 * CH; i += 256) {
        sWl[i / CH][i % CH] = Wl[i];
        sWr[i / CH][i % CH] = Wr[i];
    }
    for (int i = threadIdx.x; i < 2 * CH; i += 256) sWe[i / CH][i % CH] = We[i];
    for (int i = threadIdx.x; i < CH; i += 256) {
        sbl[i] = bl[i]; sbr[i] = br[i]; satt[i] = att[i];
    }
    __syncthreads();

    int lane = threadIdx.x & 63;
    int wv = (blockIdx.x << 2) + (threadIdx.x >> 6);
    int nw = gridDim.x << 2;

    for (int e = wv; e < ET; e += nw) {
        int src, dst; float ea0, ea1;
        if (e < NE) {
            src = ei[e]; dst = ei[NE + e];
            ea0 = ew[2 * e]; ea1 = ew[2 * e + 1];
        } else {
            src = dst = e - NE; ea0 = 0.f; ea1 = 0.f;
        }
        if ((u32)src >= NN) src = 0;
        if ((u32)dst >= NN) dst = 0;
        float xs[6], xd[6];
#pragma unroll
        for (int k = 0; k < 6; ++k) {
            xs[k] = x[src * 6 + k];
            xd[k] = x[dst * 6 + k];
        }
        float p = 0.f;
#pragma unroll
        for (int hh = 0; hh < 2; ++hh) {
            int c = lane + (hh << 6);
            float xlv = sbl[c], xrv = sbr[c];
#pragma unroll
            for (int k = 0; k < 6; ++k) {
                xlv += xs[k] * sWl[k][c];
                xrv += xd[k] * sWr[k][c];
            }
            float m = xlv + xrv + ea0 * sWe[0][c] + ea1 * sWe[1][c];
            m = m > 0.f ? m : 0.2f * m;      // leaky_relu(0.2)
            p += m * satt[c];
        }
#pragma unroll
        for (int off = 32; off; off >>= 1) p += __shfl_down(p, off, 64);
        if (lane == 0) {
            p = fminf(fmaxf(p, -60.f), 60.f);
            float ev = __expf(p);
            out_alpha[e] = ev;
            atomicAdd(den + dst, ev);
        }
    }
}

// ---------------------------------------------------------------------------
// E2: out_alpha[e] /= den[dst]   (deg == sum(alpha) == 1 identically -> no deg)
// ---------------------------------------------------------------------------
__global__ __launch_bounds__(256) void k_alpha(
    const int* __restrict__ ei, const float* __restrict__ den,
    float* __restrict__ out_alpha)
{
    int e = blockIdx.x * 256 + threadIdx.x;
    if (e >= ET) return;
    int dst = (e < NE) ? ei[NE + e] : e - NE;
    if ((u32)dst >= NN) dst = 0;
    float dn = den[dst];
    out_alpha[e] = (dn > 1e-30f) ? out_alpha[e] / dn : 0.f;
}

// ---------------------------------------------------------------------------
// k_h_csr (wave/node): h[n,:] = relu( sum_e alpha_e * xl(src_e,:) + b_gat )
// xl recomputed from x[src] (24B, cache-hot). One coalesced 512B store/node.
// ---------------------------------------------------------------------------
__global__ __launch_bounds__(256) void k_h_csr(
    const u32* __restrict__ rowptr, const u32* __restrict__ eid,
    const int* __restrict__ ei, const float* __restrict__ alpha,
    const float* __restrict__ x,
    const float* __restrict__ Wl, const float* __restrict__ bl,
    const float* __restrict__ bgat, float* __restrict__ h)
{
    __shared__ float sWl[6][CH];
    __shared__ float sbl[CH], sbg[CH];
    for (int i = threadIdx.x; i < 6 * CH; i += 256) sWl[i / CH][i % CH] = Wl[i];
    for (int i = threadIdx.x; i < CH; i += 256) { sbl[i] = bl[i]; sbg[i] = bgat[i]; }
    __syncthreads();

    int n = (blockIdx.x << 2) + (threadIdx.x >> 6);   // grid sized so n < NN
    int lane = threadIdx.x & 63;
    int c0 = lane * 2;
    u32 p0 = rowptr[n], p1 = rowptr[n + 1];
    float a0 = 0.f, a1 = 0.f;
    for (u32 p = p0; p < p1; ++p) {
        u32 e = eid[p];
        int src = (e < NE) ? ei[e] : (int)e - NE;
        if ((u32)src >= NN) src = 0;
        float al = alpha[e];
        float xs[6];
#pragma unroll
        for (int k = 0; k < 6; ++k) xs[k] = x[src * 6 + k];
        float v0 = sbl[c0], v1 = sbl[c0 + 1];
#pragma unroll
        for (int k = 0; k < 6; ++k) {
            v0 += xs[k] * sWl[k][c0];
            v1 += xs[k] * sWl[k][c0 + 1];
        }
        a0 += al * v0;
        a1 += al * v1;
    }
    float r0 = a0 + sbg[c0];     r0 = r0 > 0.f ? r0 : 0.f;
    float r1 = a1 + sbg[c0 + 1]; r1 = r1 > 0.f ? r1 : 0.f;
    ((float2*)h)[(size_t)n * 64 + lane] = make_float2(r0, r1);
}

// ---------------------------------------------------------------------------
// GEMM1: hg = h @ W2.  Thread owns column c: W2[:,c] in 128 VGPRs; h-row
// elements are wave-uniform loads (scalar-promoted) -> pure-FMA inner loop.
// ---------------------------------------------------------------------------
__global__ __launch_bounds__(256, 2) void k_gemm1(
    const float* __restrict__ h, const float* __restrict__ W2,
    float* __restrict__ hg)
{
    int c = threadIdx.x & 127;
    int half = threadIdx.x >> 7;      // wave-uniform (waves 0,1 -> 0; 2,3 -> 1)
    float w[CH];
#pragma unroll
    for (int k = 0; k < CH; ++k) w[k] = W2[k * CH + c];
    for (int n = blockIdx.x * 2 + half; n < NN; n += gridDim.x * 2) {
        const float* row = h + (size_t)n * CH;
        float acc = 0.f;
#pragma unroll
        for (int k = 0; k < CH; ++k) acc += row[k] * w[k];
        hg[(size_t)n * CH + c] = acc;
    }
}

// ---------------------------------------------------------------------------
// k_h2_csr (wave/node): h2[n,:] = sum_e alpha_e * hg[src_e,:]
// (norm == alpha since deg == 1 identically). Coalesced float2 gathers.
// ---------------------------------------------------------------------------
__global__ __launch_bounds__(256) void k_h2_csr(
    const u32* __restrict__ rowptr, const u32* __restrict__ eid,
    const int* __restrict__ ei, const float* __restrict__ alpha,
    const float* __restrict__ hg, float* __restrict__ h2)
{
    int n = (blockIdx.x << 2) + (threadIdx.x >> 6);
    int lane = threadIdx.x & 63;
    u32 p0 = rowptr[n], p1 = rowptr[n + 1];
    float a0 = 0.f, a1 = 0.f;
    for (u32 p = p0; p < p1; ++p) {
        u32 e = eid[p];
        int src = (e < NE) ? ei[e] : (int)e - NE;
        if ((u32)src >= NN) src = 0;
        float al = alpha[e];
        float2 g = ((const float2*)hg)[(size_t)src * 64 + lane];
        a0 += al * g.x;
        a1 += al * g.y;
    }
    ((float2*)h2)[(size_t)n * 64 + lane] = make_float2(a0, a1);
}

// ---------------------------------------------------------------------------
// K_out: out[n,:] = relu(h2 + b_gcn) @ W3 + b3    (wave per node)
// ---------------------------------------------------------------------------
__global__ __launch_bounds__(256) void k_final(
    const float* __restrict__ h2, const float* __restrict__ bgcn,
    const float* __restrict__ W3, const float* __restrict__ b3,
    float* __restrict__ out)
{
    __shared__ float sW30[CH], sW31[CH], sbg[CH];
    for (int i = threadIdx.x; i < CH; i += 256) {
        sW30[i] = W3[2 * i];
        sW31[i] = W3[2 * i + 1];
        sbg[i]  = bgcn[i];
    }
    __syncthreads();
    int n = (blockIdx.x << 2) + (threadIdx.x >> 6);
    int lane = threadIdx.x & 63;
    float a0 = 0.f, a1 = 0.f;
#pragma unroll
    for (int hh = 0; hh < 2; ++hh) {
        int c = lane + (hh << 6);
        float v = h2[(size_t)n * CH + c] + sbg[c];
        v = v > 0.f ? v : 0.f;
        a0 += v * sW30[c];
        a1 += v * sW31[c];
    }
#pragma unroll
    for (int off = 32; off; off >>= 1) {
        a0 += __shfl_down(a0, off, 64);
        a1 += __shfl_down(a1, off, 64);
    }
    if (lane == 0) {
        out[n * 2]     = a0 + b3[0];
        out[n * 2 + 1] = a1 + b3[1];
    }
}

// ---------------------------------------------------------------------------
extern "C" void kernel_launch(void* const* d_in, const int* in_sizes, int n_in,
                              void* d_out, int out_size, void* d_ws, size_t ws_size,
                              hipStream_t stream)
{
    const float* x    = (const float*)d_in[0];
    const int*   ei   = (const int*)d_in[1];
    const float* ew   = (const float*)d_in[2];
    const float* Wl   = (const float*)d_in[3];
    const float* bl   = (const float*)d_in[4];
    const float* Wr   = (const float*)d_in[5];
    const float* br   = (const float*)d_in[6];
    const float* We   = (const float*)d_in[7];
    const float* att  = (const float*)d_in[8];
    const float* bgat = (const float*)d_in[9];
    const float* W2   = (const float*)d_in[10];
    const float* bgcn = (const float*)d_in[11];
    const float* W3   = (const float*)d_in[12];
    const float* b3   = (const float*)d_in[13];

    float* out       = (float*)d_out;          // chunk0: out [N,2] f32
    float* out_idx   = out + 200000;           // chunk1: stack([src,dst]) [2,ET]
    float* out_alpha = out + 200000 + 2 * ET;  // chunk2: alpha [ET,1]

    // workspace (110.0 MB): A[NN*CH] | B[NN*CH] | eid[ET] | cnt/den[NN] | rowptr[NN+1] | bsum[512]
    float* ws     = (float*)d_ws;
    float* A      = ws;                        // h(relu), then h2
    float* B      = A + (size_t)NN * CH;       // hg
    u32*   eid    = (u32*)(B + (size_t)NN * CH);
    u32*   cnt    = eid + ET;                  // cnt, then den (aliased)
    float* den    = (float*)cnt;
    u32*   rowptr = cnt + NN;
    u32*   bsum   = rowptr + NN + 1;

    const int EB = (ET + 255) / 256;           // edge-parallel blocks
    const int SB = (NN + 255) / 256;           // 391 scan blocks

    // --- CSR build ---
    hipMemsetAsync(cnt, 0, NN * sizeof(u32), stream);
    k_idx<<<EB, 256, 0, stream>>>(ei, out_idx);
    k_deg<<<EB, 256, 0, stream>>>(ei, cnt);
    k_scanA<<<SB, 256, 0, stream>>>(cnt, bsum);
    k_scanB<<<1, 512, 0, stream>>>(bsum, SB);
    k_scanC<<<SB, 256, 0, stream>>>(cnt, bsum, rowptr);
    hipMemsetAsync(cnt, 0, NN * sizeof(u32), stream);
    k_scatter<<<EB, 256, 0, stream>>>(ei, rowptr, cnt, eid);

    // --- GATv2 attention ---
    hipMemsetAsync(den, 0, NN * sizeof(float), stream);
    k_logits<<<8192, 256, 0, stream>>>(ei, ew, x, Wl, bl, Wr, br, We, att,
                                       out_alpha, den);
    k_alpha<<<EB, 256, 0, stream>>>(ei, den, out_alpha);

    // --- aggregation + MLP (gather, no atomics) ---
    k_h_csr<<<NN / 4, 256, 0, stream>>>(rowptr, eid, ei, out_alpha, x, Wl, bl,
                                        bgat, A);
    k_gemm1<<<2048, 256, 0, stream>>>(A, W2, B);
    k_h2_csr<<<NN / 4, 256, 0, stream>>>(rowptr, eid, ei, out_alpha, B, A);
    k_final<<<NN / 4, 256, 0, stream>>>(A, bgcn, W3, b3, out);
}